// Round 11
// baseline (1697.641 us; speedup 1.0000x reference)
//
#include <hip/hip_runtime.h>

#define NB 64
#define NC 32
#define NE 4096
#define NPIX 256
#define NTOT (NB*NC*NPIX)   // 524288
#define IDXW 341            // 1+4+16+64+256
#define TPB 1024
#define MARGIN 1e-2f

__device__ __forceinline__ double cubicw(double x) {
  const double A = -0.75;
  x = fabs(x);
  if (x <= 1.0) return ((A + 2.0) * x - (A + 3.0)) * x * x + 1.0;
  if (x < 2.0)  return A * (((x - 5.0) * x + 8.0) * x - 4.0);
  return 0.0;
}

// One block per image; zero grid barriers; all cross-thread deps are
// within-block (__syncthreads). emb_t is written redundantly by every block
// (identical values; each thread reads only the entries it wrote itself).
__global__ __launch_bounds__(TPB, 4) void k_fused(
    const float* __restrict__ z, const float* __restrict__ emb,
    const float* __restrict__ phi_w, const float* __restrict__ phi_b,
    double* __restrict__ z_res, float* __restrict__ emb_t,
    double* __restrict__ loss_d, unsigned* __restrict__ counter,
    float* __restrict__ out_zhat, float* __restrict__ out_loss,
    float* __restrict__ out_idx)
{
  __shared__ double lds[8192];              // 64 KB, overlaid per phase
  double* rv   = lds;                       // [8][32] f64 pooled rows
  float*  rvf  = (float*)(lds + 256);       // [32][8] f32, k-major (float4-able)
  float*  wdm  = (float*)(lds + 384);       // [16][8] stage-1 per-wave mins
  double* wd   = lds + 448;                 // [16][8] f64
  int*    wi   = (int*)(lds + 576);         // [16][8]
  float*  wmv  = (float*)(lds + 640);       // [8]
  int* idx_loc = (int*)(lds + 644);         // [256]

  const int tid = threadIdx.x;
  const int b = blockIdx.x;
  const int pix = tid & 255, sub = tid >> 8;
  const int px = pix & 15, py = pix >> 4;
  const int lane = tid & 63, wave = tid >> 6;

  // Poison-tolerant one-time init (idempotent CAS; sums can never equal poison).
  if (tid == 0)  atomicCAS((unsigned long long*)loss_d, 0xAAAAAAAAAAAAAAAAull, 0ull);
  if (tid == 64) atomicCAS(counter, 0xAAAAAAAAu, 0u);

  // ---- setup: thread owns entries e = 4*tid+p. Transpose + |e|^2 (exact
  // 4-channel-group ascending sum order, matching prior passing kernels). ----
  double esq[4] = {0.0, 0.0, 0.0, 0.0};
  #pragma unroll
  for (int c0 = 0; c0 < NC; c0 += 4) {
    float4 r0 = *(const float4*)(emb + (4*tid+0)*NC + c0);
    float4 r1 = *(const float4*)(emb + (4*tid+1)*NC + c0);
    float4 r2 = *(const float4*)(emb + (4*tid+2)*NC + c0);
    float4 r3 = *(const float4*)(emb + (4*tid+3)*NC + c0);
    esq[0] += (double)r0.x*r0.x + (double)r0.y*r0.y + (double)r0.z*r0.z + (double)r0.w*r0.w;
    esq[1] += (double)r1.x*r1.x + (double)r1.y*r1.y + (double)r1.z*r1.z + (double)r1.w*r1.w;
    esq[2] += (double)r2.x*r2.x + (double)r2.y*r2.y + (double)r2.z*r2.z + (double)r2.w*r2.w;
    esq[3] += (double)r3.x*r3.x + (double)r3.y*r3.y + (double)r3.z*r3.z + (double)r3.w*r3.w;
    *(float4*)&emb_t[(c0+0)*NE + 4*tid] = make_float4(r0.x, r1.x, r2.x, r3.x);
    *(float4*)&emb_t[(c0+1)*NE + 4*tid] = make_float4(r0.y, r1.y, r2.y, r3.y);
    *(float4*)&emb_t[(c0+2)*NE + 4*tid] = make_float4(r0.z, r1.z, r2.z, r3.z);
    *(float4*)&emb_t[(c0+3)*NE + 4*tid] = make_float4(r0.w, r1.w, r2.w, r3.w);
  }
  for (int i = tid; i < NC*NPIX; i += TPB)
    z_res[b*NC*NPIX + i] = (double)z[b*NC*NPIX + i];
  __syncthreads();

  const int phs[5]  = {1, 2, 4, 8, 16};
  // ticks = np.linspace(1/12, 11/12, 4) f64: si=2 real-arithmetic tie breaks
  // to pi=2 via 2-ulp linspace rounding (verified by exact mantissa calc).
  const int pis[5]  = {0, 1, 2, 2, 3};
  const int offs[5] = {0, 1, 5, 21, 85};
  double lsum_tot = 0.0;

  for (int si = 0; si < 5; si++) {
    const int ph = phs[si], f = 16 / ph, R = ph * ph;
    const int pi = pis[si];

    // ================= argmin: rows in groups of 8 =================
    for (int r0 = 0; r0 < R; r0 += 8) {
      int valid = (R - r0 < 8) ? (R - r0) : 8;
      if (tid < 256) {                       // fused area-pool (f64, exact order)
        int j = tid >> 5, c = tid & 31;
        int jj = (j < valid) ? j : (valid - 1);
        int n = r0 + jj;
        int x = n % ph, y = n / ph;
        const double* base = z_res + ((b*NC + c)*16 + y*f)*16 + x*f;
        double s = 0.0;
        for (int dy = 0; dy < f; dy++)
          for (int dx = 0; dx < f; dx++) s += base[dy*16 + dx];
        double rvv = s / (double)(f * f);
        rv[j*NC + c] = rvv;
        rvf[c*8 + j] = (float)rvv;
      }
      __syncthreads();

      // ---- stage 1: f32 distances, per-row block min (approximate) ----
      float fmin[8];
      #pragma unroll
      for (int j = 0; j < 8; j++) fmin[j] = 1e30f;
      {
        float4 acc[8];                      // acc[j].{x..w} = entries p=0..3
        #pragma unroll
        for (int j = 0; j < 8; j++) acc[j] = make_float4(0.f, 0.f, 0.f, 0.f);
        #pragma unroll 4
        for (int k = 0; k < NC; k++) {
          float4 ev = *(const float4*)&emb_t[k*NE + 4*tid];   // 16B/lane coalesced
          float4 ra = *(const float4*)&rvf[k*8];              // rows 0-3 (broadcast)
          float4 rb = *(const float4*)&rvf[k*8 + 4];          // rows 4-7
          float rj[8] = {ra.x, ra.y, ra.z, ra.w, rb.x, rb.y, rb.z, rb.w};
          #pragma unroll
          for (int j = 0; j < 8; j++) {
            acc[j].x += rj[j]*ev.x; acc[j].y += rj[j]*ev.y;
            acc[j].z += rj[j]*ev.z; acc[j].w += rj[j]*ev.w;
          }
        }
        #pragma unroll
        for (int j = 0; j < 8; j++) {
          float d0 = (float)esq[0] - 2.0f*acc[j].x;
          float d1 = (float)esq[1] - 2.0f*acc[j].y;
          float d2 = (float)esq[2] - 2.0f*acc[j].z;
          float d3 = (float)esq[3] - 2.0f*acc[j].w;
          fmin[j] = fminf(fminf(fminf(fminf(fmin[j], d0), d1), d2), d3);
        }
      }
      #pragma unroll
      for (int j = 0; j < 8; j++) {
        float m = fmin[j];
        #pragma unroll
        for (int off = 32; off >= 1; off >>= 1)
          m = fminf(m, __shfl_xor(m, off, 64));
        if (lane == 0) wdm[wave*8 + j] = m;
      }
      __syncthreads();
      if (tid < 8) {
        float m = wdm[tid];
        #pragma unroll
        for (int w2 = 1; w2 < 16; w2++) m = fminf(m, wdm[w2*8 + tid]);
        wmv[tid] = m;
      }
      __syncthreads();

      // ---- stage 2: exact f64 rerank of flagged threads only.
      // Any entry whose exact f64 distance equals the true min has f32
      // distance within 2*err(~2e-4) of m -> its thread is flagged (margin
      // 1e-2 = 50x safety). So the lex-min below == full-f64 argmin exactly.
      double dbest[8]; int dbidx[8];
      #pragma unroll
      for (int j = 0; j < 8; j++) { dbest[j] = 1e300; dbidx[j] = 0x7FFFFFFF; }
      bool anyflag = false;
      #pragma unroll
      for (int j = 0; j < 8; j++) anyflag = anyflag || (fmin[j] <= wmv[j] + MARGIN);
      if (anyflag) {
        #pragma unroll
        for (int p = 0; p < 4; p++) {        // ascending e: ties keep lowest
          int e = 4*tid + p;
          const float* er = emb + e*NC;
          #pragma unroll
          for (int j = 0; j < 8; j++) {
            if (fmin[j] <= wmv[j] + MARGIN) {
              double dot = 0.0;
              for (int k = 0; k < NC; k++)   // k-ascending f64 sum (bit-identical)
                dot += rv[j*NC + k] * (double)er[k];
              double d = esq[p] - 2.0*dot;
              if (d < dbest[j]) { dbest[j] = d; dbidx[j] = e; }
            }
          }
        }
      }
      #pragma unroll
      for (int j = 0; j < 8; j++) {          // lex-min butterfly (d, idx)
        double d = dbest[j]; int bi = dbidx[j];
        #pragma unroll
        for (int off = 32; off >= 1; off >>= 1) {
          double od = __shfl_xor(d, off, 64);
          int oi = __shfl_xor(bi, off, 64);
          if (od < d || (od == d && oi < bi)) { d = od; bi = oi; }
        }
        if (lane == 0) { wd[wave*8 + j] = d; wi[wave*8 + j] = bi; }
      }
      __syncthreads();
      if (tid < valid) {
        double d = wd[tid]; int bi = wi[tid];
        #pragma unroll
        for (int w2 = 1; w2 < 16; w2++) {
          double od = wd[w2*8 + tid]; int oi = wi[w2*8 + tid];
          if (od < d || (od == d && oi < bi)) { d = od; bi = oi; }
        }
        idx_loc[r0 + tid] = bi;
        out_idx[b*IDXW + offs[si] + r0 + tid] = (float)bi;
      }
      __syncthreads();
    }

    // ================= upsample into qimg (LDS), then phi =================
    double* qimg = lds;                     // full 64 KB overlay
    if (si < 4) {
      // snapshot bicubic taps from idx_loc BEFORE qimg overwrites LDS
      double scale = (double)ph / 16.0;
      double srcy = ((double)py + 0.5) * scale - 0.5;
      double fiy = floor(srcy); int iy0 = (int)fiy; double fy = srcy - fiy;
      double srcx = ((double)px + 0.5) * scale - 0.5;
      double fxx = floor(srcx); int ix0 = (int)fxx; double fx = srcx - fxx;
      double wy[4], wx[4]; int taps[16];
      #pragma unroll
      for (int m = 0; m < 4; m++) {
        wy[m] = cubicw(fy - (double)(m - 1));
        wx[m] = cubicw(fx - (double)(m - 1));
      }
      #pragma unroll
      for (int m = 0; m < 4; m++) {
        int iy = min(max(iy0 + m - 1, 0), ph - 1);
        #pragma unroll
        for (int k = 0; k < 4; k++) {
          int ix = min(max(ix0 + k - 1, 0), ph - 1);
          taps[m*4 + k] = idx_loc[iy*ph + ix];
        }
      }
      __syncthreads();                      // all taps snapshotted; LDS free
      for (int c = sub; c < NC; c += 4) {   // exact H-then-W sum order
        double s = 0.0;
        #pragma unroll
        for (int k = 0; k < 4; k++) {
          double t = 0.0;
          #pragma unroll
          for (int m = 0; m < 4; m++)
            t += wy[m] * (double)emb[taps[m*4 + k]*NC + c];
          s += wx[k] * t;
        }
        qimg[c*NPIX + pix] = s;
      }
    } else {
      int myidx = idx_loc[pix];
      __syncthreads();                      // snapshot before overlay
      for (int c = sub; c < NC; c += 4)
        qimg[c*NPIX + pix] = (double)emb[myidx*NC + c];
    }
    __syncthreads();

    // phi: 0.5*x + 0.5*(conv3x3(x)+bias); residual update + loss
    {
      double acc[8];
      #pragma unroll
      for (int j = 0; j < 8; j++) acc[j] = 0.0;
      const float* w = phi_w + pi*NC*NC*9;
      for (int ci = 0; ci < NC; ci++) {
        double wv[9];
        #pragma unroll
        for (int ky = 0; ky < 3; ky++) {
          int yy = py + ky - 1;
          #pragma unroll
          for (int kx = 0; kx < 3; kx++) {
            int xx = px + kx - 1;
            wv[ky*3 + kx] = (yy >= 0 && yy < 16 && xx >= 0 && xx < 16)
                            ? qimg[ci*NPIX + yy*16 + xx] : 0.0;
          }
        }
        #pragma unroll
        for (int j = 0; j < 8; j++) {
          const float* wp = w + ((sub*8 + j)*NC + ci)*9;   // wave-uniform
          double a = acc[j];
          #pragma unroll
          for (int k = 0; k < 9; k++) a += wv[k] * (double)wp[k];
          acc[j] = a;
        }
      }
      #pragma unroll
      for (int j = 0; j < 8; j++) {
        int co = sub*8 + j;
        int i = co*NPIX + pix;
        int gi = b*NC*NPIX + i;
        double val = qimg[i]*0.5 + (acc[j] + (double)phi_b[pi*NC + co])*0.5;
        double zr = z_res[gi] - val;
        z_res[gi] = zr;
        if (si == 4) out_zhat[gi] = (float)((double)z[gi] - zr);
        lsum_tot += zr * zr;                // z_hat - z == -z_res
      }
    }
    __syncthreads();                        // z_res/LDS ready for next scale
  }

  // ---- loss: block reduce + one device atomic; last block finalizes ----
  lds[tid] = lsum_tot;
  __syncthreads();
  for (int s = 512; s > 0; s >>= 1) {
    if (tid < s) lds[tid] += lds[tid + s];
    __syncthreads();
  }
  if (tid == 0) {
    atomicAdd(loss_d, lds[0]);
    __threadfence();
    unsigned old = atomicAdd(counter, 1u);
    if (old == NB - 1) {
      double tot = atomicAdd(loss_d, 0.0);
      *out_loss = (float)(tot * (1.25 / (5.0 * (double)NTOT)));
    }
  }
}

extern "C" void kernel_launch(void* const* d_in, const int* in_sizes, int n_in,
                              void* d_out, int out_size, void* d_ws, size_t ws_size,
                              hipStream_t stream) {
  const float* z     = (const float*)d_in[0];   // [64,32,16,16]
  const float* emb   = (const float*)d_in[1];   // [4096,32]
  const float* phi_w = (const float*)d_in[2];   // [4,32,32,3,3]
  const float* phi_b = (const float*)d_in[3];   // [4,32]

  float* out      = (float*)d_out;
  float* out_zhat = out;
  float* out_loss = out + NTOT;
  float* out_idx  = out + NTOT + 1; // [64,341] as floats

  double* ws        = (double*)d_ws;
  double* z_res     = ws;                        // 524288 f64
  double* loss_d    = z_res + NTOT;              // 1 f64
  float* emb_t      = (float*)(loss_d + 1);      // 131072 f32
  unsigned* counter = (unsigned*)(emb_t + NE*NC);

  k_fused<<<NB, TPB, 0, stream>>>(z, emb, phi_w, phi_b,
                                  z_res, emb_t, loss_d, counter,
                                  out_zhat, out_loss, out_idx);
}